// Round 2
// baseline (358.692 us; speedup 1.0000x reference)
//
#include <hip/hip_runtime.h>
#include <hip/hip_bf16.h>

typedef unsigned short u16;

#define BDIM 8
#define LDIM 8192
#define KDIM 256      // C
#define DDIM 256      // D
#define MTOT 65536    // B*L
#define NDIM 1536     // 6*D
#define TCH  32       // scan chunk length
#define NCH  256      // chunks per sequence

typedef float floatx4 __attribute__((ext_vector_type(4)));
typedef short bf16x8 __attribute__((ext_vector_type(8)));

__device__ __forceinline__ u16 f2bf(float f) {
  union { __hip_bfloat16 h; u16 u; } c;
  c.h = __float2bfloat16(f);
  return c.u;
}
__device__ __forceinline__ float bf2f(u16 u) {
  union { unsigned int i; float f; } c;
  c.i = ((unsigned int)u) << 16;
  return c.f;
}
__device__ __forceinline__ float sigmoidf_fast(float x) {
  return __builtin_amdgcn_rcpf(1.0f + __expf(-x));
}
// async global->LDS, 16B per lane; LDS dest = wave-uniform base + lane*16
__device__ __forceinline__ void gll16(const u16* g, u16* l) {
  __builtin_amdgcn_global_load_lds((const __attribute__((address_space(1))) void*)g,
                                   (__attribute__((address_space(3))) void*)l, 16, 0, 0);
}

// ---------------------------------------------------------------------------
// Prep: WcatT[n][k] = W_g[k][n%256] bf16; groups: h_f,z_f,s_f,h_b,z_b,s_b
// ---------------------------------------------------------------------------
__global__ void prep_weights(const float* __restrict__ Wh1, const float* __restrict__ Wz1,
                             const float* __restrict__ Ws1, const float* __restrict__ Wh_1,
                             const float* __restrict__ Wz_1, const float* __restrict__ Ws_1,
                             const float* __restrict__ bh1, const float* __restrict__ bz1,
                             const float* __restrict__ bs1, const float* __restrict__ bh_1,
                             const float* __restrict__ bz_1, const float* __restrict__ bs_1,
                             u16* __restrict__ WcatT, float* __restrict__ bcat) {
  const int n = blockIdx.x;       // 0..1535
  const int k = threadIdx.x;      // 0..255
  const int g = n >> 8, d = n & 255;
  const float* W; const float* bb;
  switch (g) {
    case 0: W = Wh1;  bb = bh1;  break;
    case 1: W = Wz1;  bb = bz1;  break;
    case 2: W = Ws1;  bb = bs1;  break;
    case 3: W = Wh_1; bb = bh_1; break;
    case 4: W = Wz_1; bb = bz_1; break;
    default: W = Ws_1; bb = bs_1; break;
  }
  WcatT[(size_t)n * KDIM + k] = f2bf(W[k * DDIM + d]);
  if (k == 0) bcat[n] = bb[d];
}

// ---------------------------------------------------------------------------
// Convert xs fp32 -> bf16
// ---------------------------------------------------------------------------
__global__ void convert_xs(const float* __restrict__ xs, u16* __restrict__ Abf) {
  size_t i = ((size_t)blockIdx.x * 256 + threadIdx.x) * 8;
  const float4* s = (const float4*)(xs + i);
  float4 f0 = s[0], f1 = s[1];
  union { u16 u[8]; uint4 v; } t;
  t.u[0] = f2bf(f0.x); t.u[1] = f2bf(f0.y); t.u[2] = f2bf(f0.z); t.u[3] = f2bf(f0.w);
  t.u[4] = f2bf(f1.x); t.u[5] = f2bf(f1.y); t.u[6] = f2bf(f1.z); t.u[7] = f2bf(f1.w);
  *(uint4*)(Abf + i) = t.v;
}

// ---------------------------------------------------------------------------
// GEMM: G[m][n] = A[m][:] . WcatT[n][:] + bcat[n], bf16 MFMA 16x16x32.
// 128x128 tile, BK=32, 4 waves 2x2, global_load_lds width-16 staging.
// LDS layout: 16B block index bi = row*4 + kq  (kq = k/8 within BK).
// Grid swizzle: xcd = blk&7 owns m-band [xcd*64 mt], nt innermost ->
// per-XCD A footprint 4MB (=L2), B (0.75MB) resident.
// ---------------------------------------------------------------------------
__global__ __launch_bounds__(256) void gemm_kernel(const u16* __restrict__ Abf,
                                                   const u16* __restrict__ WcatT,
                                                   const float* __restrict__ bcat,
                                                   u16* __restrict__ G) {
  __shared__ __align__(16) u16 As[4096];   // 128 rows x 32 k
  __shared__ __align__(16) u16 Bs[4096];
  const int tid = threadIdx.x;
  const int lane = tid & 63, wave = tid >> 6;
  const int wm = wave >> 1, wn = wave & 1;
  const int q = lane >> 4, r = lane & 15;

  const int xcd = blockIdx.x & 7;
  const int li  = blockIdx.x >> 3;      // 0..767
  const int mt  = xcd * 64 + li / 12;   // 0..511
  const int nt  = li % 12;              // 0..11
  const int m0 = mt * 128, n0 = nt * 128;

  const int bi0 = wave * 128 + lane;    // 16B-block index this lane stages
  const int bi1 = bi0 + 64;
  const u16* gA0 = Abf   + (size_t)(m0 + (bi0 >> 2)) * KDIM + (bi0 & 3) * 8;
  const u16* gA1 = Abf   + (size_t)(m0 + (bi1 >> 2)) * KDIM + (bi1 & 3) * 8;
  const u16* gB0 = WcatT + (size_t)(n0 + (bi0 >> 2)) * KDIM + (bi0 & 3) * 8;
  const u16* gB1 = WcatT + (size_t)(n0 + (bi1 >> 2)) * KDIM + (bi1 & 3) * 8;
  u16* lA0 = As + wave * 1024;
  u16* lA1 = As + wave * 1024 + 512;
  u16* lB0 = Bs + wave * 1024;
  u16* lB1 = Bs + wave * 1024 + 512;

  floatx4 acc[4][4];
  floatx4 z4 = {0.f, 0.f, 0.f, 0.f};
#pragma unroll
  for (int i = 0; i < 4; i++)
#pragma unroll
    for (int j = 0; j < 4; j++) acc[i][j] = z4;

  for (int k0 = 0; k0 < KDIM; k0 += 32) {
    gll16(gA0 + k0, lA0);
    gll16(gA1 + k0, lA1);
    gll16(gB0 + k0, lB0);
    gll16(gB1 + k0, lB1);
    __syncthreads();
    bf16x8 af[4], bv[4];
#pragma unroll
    for (int i = 0; i < 4; i++)
      af[i] = *(const bf16x8*)(As + ((wm * 64 + i * 16 + r) * 4 + q) * 8);
#pragma unroll
    for (int j = 0; j < 4; j++)
      bv[j] = *(const bf16x8*)(Bs + ((wn * 64 + j * 16 + r) * 4 + q) * 8);
#pragma unroll
    for (int i = 0; i < 4; i++)
#pragma unroll
      for (int j = 0; j < 4; j++)
        acc[i][j] = __builtin_amdgcn_mfma_f32_16x16x32_bf16(af[i], bv[j], acc[i][j], 0, 0, 0);
    __syncthreads();
  }

  // C/D layout: col = lane&15, row = (lane>>4)*4 + reg  [m89/m91]
  float bvals[4];
#pragma unroll
  for (int j = 0; j < 4; j++) bvals[j] = bcat[n0 + wn * 64 + j * 16 + r];
#pragma unroll
  for (int i = 0; i < 4; i++) {
#pragma unroll
    for (int reg = 0; reg < 4; reg++) {
      size_t grow = (size_t)(m0 + wm * 64 + i * 16 + q * 4 + reg);
      u16* dst = G + grow * NDIM + n0 + wn * 64 + r;
#pragma unroll
      for (int j = 0; j < 4; j++)
        dst[j * 16] = f2bf(acc[i][j][reg] + bvals[j]);
    }
  }
}

// ---------------------------------------------------------------------------
// Scan phase A: per-chunk affine summary, vectorized 8 d / thread.
// unit u = dir*2048 + b*256 + c ; 32 threads per unit (sub = d/8).
// ---------------------------------------------------------------------------
__global__ __launch_bounds__(256) void scan_phaseA(const u16* __restrict__ G,
                                                   float* __restrict__ Acc,
                                                   float* __restrict__ Bcc) {
  const int slot = threadIdx.x >> 5, sub = threadIdx.x & 31;
  const int u = blockIdx.x * 8 + slot;         // 0..4095
  const int c = u & 255, b = (u >> 8) & 7, dir = u >> 11;
  const int hoff = dir ? 768 : 0;
  const u16* p0 = G + (size_t)b * LDIM * NDIM + hoff + sub * 8;
  float h[8], P[8];
#pragma unroll
  for (int e = 0; e < 8; ++e) { h[e] = 0.f; P[e] = 1.f; }
#pragma unroll 4
  for (int i = 0; i < TCH; ++i) {
    const int t = dir ? (c * TCH + (TCH - 1 - i)) : (c * TCH + i);
    const u16* p = p0 + (size_t)t * NDIM;
    uint4 hv = *(const uint4*)p;
    uint4 zv = *(const uint4*)(p + 256);
    const u16* hq = (const u16*)&hv;
    const u16* zq = (const u16*)&zv;
#pragma unroll
    for (int e = 0; e < 8; ++e) {
      float z = sigmoidf_fast(bf2f(zq[e]));
      float a = 1.f - z;
      h[e] = fmaf(a, h[e], z * bf2f(hq[e]));
      P[e] *= a;
    }
  }
  float* ap = Acc + (size_t)u * 256 + sub * 8;
  float* bp = Bcc + (size_t)u * 256 + sub * 8;
  float4 v;
  v.x = P[0]; v.y = P[1]; v.z = P[2]; v.w = P[3]; *(float4*)ap = v;
  v.x = P[4]; v.y = P[5]; v.z = P[6]; v.w = P[7]; *(float4*)(ap + 4) = v;
  v.x = h[0]; v.y = h[1]; v.z = h[2]; v.w = h[3]; *(float4*)bp = v;
  v.x = h[4]; v.y = h[5]; v.z = h[6]; v.w = h[7]; *(float4*)(bp + 4) = v;
}

// ---------------------------------------------------------------------------
// Scan phase B: chain chunk summaries -> entering prefix per chunk.
// ---------------------------------------------------------------------------
__global__ void scan_phaseB(const float* __restrict__ Acc, const float* __restrict__ Bcc,
                            const float* __restrict__ h01, const float* __restrict__ h0_1,
                            float* __restrict__ Pref) {
  const int d = threadIdx.x, b = blockIdx.x, dir = blockIdx.y;
  float h = dir ? h0_1[d] : h01[d];
  if (dir == 0) {
    for (int c = 0; c < NCH; ++c) {
      size_t idx = ((size_t)b * NCH + c) * DDIM + d;
      Pref[idx] = h;
      h = fmaf(Acc[idx], h, Bcc[idx]);
    }
  } else {
    for (int c = NCH - 1; c >= 0; --c) {
      size_t idx = ((size_t)2048 + (size_t)b * NCH + c) * DDIM + d;
      Pref[idx] = h;
      h = fmaf(Acc[idx], h, Bcc[idx]);
    }
  }
}

// ---------------------------------------------------------------------------
// Scan phase C fwd: replay with prefix, out = h * sigmoid(gs_f). Vectorized.
// ---------------------------------------------------------------------------
__global__ __launch_bounds__(256) void scan_phaseC_fwd(const u16* __restrict__ G,
                                                       const float* __restrict__ Pref,
                                                       float* __restrict__ out) {
  const int slot = threadIdx.x >> 5, sub = threadIdx.x & 31;
  const int u = blockIdx.x * 8 + slot;         // 0..2047
  const int c = u & 255, b = u >> 8;
  const float* pp = Pref + (size_t)u * 256 + sub * 8;
  float4 p0 = *(const float4*)pp, p1 = *(const float4*)(pp + 4);
  float h[8] = {p0.x, p0.y, p0.z, p0.w, p1.x, p1.y, p1.z, p1.w};
  const u16* g0 = G + (size_t)b * LDIM * NDIM + sub * 8;
  float* o0 = out + (size_t)b * LDIM * DDIM + sub * 8;
#pragma unroll 4
  for (int i = 0; i < TCH; ++i) {
    const int t = c * TCH + i;
    const u16* p = g0 + (size_t)t * NDIM;
    uint4 hv = *(const uint4*)p;
    uint4 zv = *(const uint4*)(p + 256);
    uint4 sv = *(const uint4*)(p + 512);
    const u16* hq = (const u16*)&hv;
    const u16* zq = (const u16*)&zv;
    const u16* sq = (const u16*)&sv;
    float o[8];
#pragma unroll
    for (int e = 0; e < 8; ++e) {
      float z = sigmoidf_fast(bf2f(zq[e]));
      h[e] = fmaf(1.f - z, h[e], z * bf2f(hq[e]));
      o[e] = h[e] * sigmoidf_fast(bf2f(sq[e]));
    }
    float* op = o0 + (size_t)t * DDIM;
    float4 v;
    v.x = o[0]; v.y = o[1]; v.z = o[2]; v.w = o[3]; *(float4*)op = v;
    v.x = o[4]; v.y = o[5]; v.z = o[6]; v.w = o[7]; *(float4*)(op + 4) = v;
  }
}

// ---------------------------------------------------------------------------
// Scan phase C bwd: descending replay, out += h * sigmoid(gs_b).
// ---------------------------------------------------------------------------
__global__ __launch_bounds__(256) void scan_phaseC_bwd(const u16* __restrict__ G,
                                                       const float* __restrict__ Pref,
                                                       float* __restrict__ out) {
  const int slot = threadIdx.x >> 5, sub = threadIdx.x & 31;
  const int u = blockIdx.x * 8 + slot;         // 0..2047
  const int c = u & 255, b = u >> 8;
  const float* pp = Pref + (size_t)(2048 + u) * 256 + sub * 8;
  float4 p0 = *(const float4*)pp, p1 = *(const float4*)(pp + 4);
  float h[8] = {p0.x, p0.y, p0.z, p0.w, p1.x, p1.y, p1.z, p1.w};
  const u16* g0 = G + (size_t)b * LDIM * NDIM + sub * 8;
  float* o0 = out + (size_t)b * LDIM * DDIM + sub * 8;
#pragma unroll 4
  for (int i = 0; i < TCH; ++i) {
    const int t = c * TCH + (TCH - 1 - i);
    const u16* p = g0 + (size_t)t * NDIM;
    uint4 hv = *(const uint4*)(p + 768);
    uint4 zv = *(const uint4*)(p + 1024);
    uint4 sv = *(const uint4*)(p + 1280);
    const u16* hq = (const u16*)&hv;
    const u16* zq = (const u16*)&zv;
    const u16* sq = (const u16*)&sv;
    float* op = o0 + (size_t)t * DDIM;
    float4 c0 = *(const float4*)op, c1 = *(const float4*)(op + 4);
    float o[8] = {c0.x, c0.y, c0.z, c0.w, c1.x, c1.y, c1.z, c1.w};
#pragma unroll
    for (int e = 0; e < 8; ++e) {
      float z = sigmoidf_fast(bf2f(zq[e]));
      h[e] = fmaf(1.f - z, h[e], z * bf2f(hq[e]));
      o[e] += h[e] * sigmoidf_fast(bf2f(sq[e]));
    }
    float4 v;
    v.x = o[0]; v.y = o[1]; v.z = o[2]; v.w = o[3]; *(float4*)op = v;
    v.x = o[4]; v.y = o[5]; v.z = o[6]; v.w = o[7]; *(float4*)(op + 4) = v;
  }
}

extern "C" void kernel_launch(void* const* d_in, const int* in_sizes, int n_in,
                              void* d_out, int out_size, void* d_ws, size_t ws_size,
                              hipStream_t stream) {
  const float* xs   = (const float*)d_in[0];
  const float* Wh1  = (const float*)d_in[1];
  const float* bh1  = (const float*)d_in[2];
  const float* Wz1  = (const float*)d_in[3];
  const float* bz1  = (const float*)d_in[4];
  const float* Ws1  = (const float*)d_in[5];
  const float* bs1  = (const float*)d_in[6];
  const float* h01  = (const float*)d_in[7];
  const float* Wh_1 = (const float*)d_in[8];
  const float* bh_1 = (const float*)d_in[9];
  const float* Wz_1 = (const float*)d_in[10];
  const float* bz_1 = (const float*)d_in[11];
  const float* Ws_1 = (const float*)d_in[12];
  const float* bs_1 = (const float*)d_in[13];
  const float* h0_1 = (const float*)d_in[14];
  float* out = (float*)d_out;

  char* ws = (char*)d_ws;
  u16* WcatT = (u16*)ws;   ws += (size_t)NDIM * KDIM * 2;   // 0.75 MB
  float* bcat = (float*)ws; ws += (size_t)NDIM * 4;         // 6 KB
  u16* Abf = (u16*)ws;     ws += (size_t)MTOT * KDIM * 2;   // 32 MB
  u16* G = (u16*)ws;       ws += (size_t)MTOT * NDIM * 2;   // 192 MB
  // Summary arrays alias the Abf region: Abf is dead once gemm completes,
  // and phaseA (first writer of Acc/Bcc) runs after gemm. 12 MB <= 32 MB.
  float* Acc  = (float*)Abf;
  float* Bcc  = Acc + (size_t)2 * BDIM * NCH * DDIM;        // 4 MB each
  float* Pref = Bcc + (size_t)2 * BDIM * NCH * DDIM;
  if ((size_t)(ws - (char*)d_ws) > ws_size) return;

  prep_weights<<<dim3(NDIM), dim3(KDIM), 0, stream>>>(
      Wh1, Wz1, Ws1, Wh_1, Wz_1, Ws_1, bh1, bz1, bs1, bh_1, bz_1, bs_1, WcatT, bcat);
  convert_xs<<<dim3(MTOT * KDIM / (256 * 8)), dim3(256), 0, stream>>>(xs, Abf);
  gemm_kernel<<<dim3(6144), dim3(256), 0, stream>>>(Abf, WcatT, bcat, G);
  scan_phaseA<<<dim3(512), dim3(256), 0, stream>>>(G, Acc, Bcc);
  scan_phaseB<<<dim3(BDIM, 2), dim3(DDIM), 0, stream>>>(Acc, Bcc, h01, h0_1, Pref);
  scan_phaseC_fwd<<<dim3(256), dim3(256), 0, stream>>>(G, Pref, out);
  scan_phaseC_bwd<<<dim3(256), dim3(256), 0, stream>>>(G, Pref, out);
}

// Round 3
// 326.592 us; speedup vs baseline: 1.0983x; 1.0983x over previous
//
#include <hip/hip_runtime.h>
#include <hip/hip_bf16.h>

typedef unsigned short u16;

#define BDIM 8
#define LDIM 8192
#define KDIM 256      // C
#define DDIM 256      // D
#define MTOT 65536    // B*L
#define NDIM 1536     // 6*D
#define TCH  32       // scan chunk length
#define NCH  256      // chunks per sequence

// Physical column layout of G (per m-row), dir f in {0,1}, base = f*768:
//   [base + 2d + 0] = h-gate col d   [base + 2d + 1] = z-gate col d  (d<256)
//   [base + 512 + d] = s-gate col d
// -> scan reads h,z for 4 consecutive d as ONE 16B load.

typedef float floatx4 __attribute__((ext_vector_type(4)));
typedef short bf16x8 __attribute__((ext_vector_type(8)));

__device__ __forceinline__ u16 f2bf(float f) {
  union { __hip_bfloat16 h; u16 u; } c;
  c.h = __float2bfloat16(f);
  return c.u;
}
__device__ __forceinline__ float bf2f(u16 u) {
  union { unsigned int i; float f; } c;
  c.i = ((unsigned int)u) << 16;
  return c.f;
}
__device__ __forceinline__ float sigmoidf_fast(float x) {
  return __builtin_amdgcn_rcpf(1.0f + __expf(-x));
}
__device__ __forceinline__ void gll16(const u16* g, u16* l) {
  __builtin_amdgcn_global_load_lds((const __attribute__((address_space(1))) void*)g,
                                   (__attribute__((address_space(3))) void*)l, 16, 0, 0);
}

// ---------------------------------------------------------------------------
// Prep: WcatT[n][k] = W(n)[k][d(n)] bf16 with the interleaved physical layout.
// ---------------------------------------------------------------------------
__global__ void prep_weights(const float* __restrict__ Wh1, const float* __restrict__ Wz1,
                             const float* __restrict__ Ws1, const float* __restrict__ Wh_1,
                             const float* __restrict__ Wz_1, const float* __restrict__ Ws_1,
                             const float* __restrict__ bh1, const float* __restrict__ bz1,
                             const float* __restrict__ bs1, const float* __restrict__ bh_1,
                             const float* __restrict__ bz_1, const float* __restrict__ bs_1,
                             u16* __restrict__ WcatT, float* __restrict__ bcat) {
  const int n = blockIdx.x;       // physical col 0..1535
  const int k = threadIdx.x;      // 0..255
  const int dir = n / 768, r = n % 768;
  int d; const float* W; const float* bb;
  if (r < 512) {
    d = r >> 1;
    if (r & 1) { W = dir ? Wz_1 : Wz1; bb = dir ? bz_1 : bz1; }
    else       { W = dir ? Wh_1 : Wh1; bb = dir ? bh_1 : bh1; }
  } else {
    d = r - 512;
    W = dir ? Ws_1 : Ws1; bb = dir ? bs_1 : bs1;
  }
  WcatT[(size_t)n * KDIM + k] = f2bf(W[k * DDIM + d]);
  if (k == 0) bcat[n] = bb[d];
}

// ---------------------------------------------------------------------------
// Convert xs fp32 -> bf16
// ---------------------------------------------------------------------------
__global__ void convert_xs(const float* __restrict__ xs, u16* __restrict__ Abf) {
  size_t i = ((size_t)blockIdx.x * 256 + threadIdx.x) * 8;
  const float4* s = (const float4*)(xs + i);
  float4 f0 = s[0], f1 = s[1];
  union { u16 u[8]; uint4 v; } t;
  t.u[0] = f2bf(f0.x); t.u[1] = f2bf(f0.y); t.u[2] = f2bf(f0.z); t.u[3] = f2bf(f0.w);
  t.u[4] = f2bf(f1.x); t.u[5] = f2bf(f1.y); t.u[6] = f2bf(f1.z); t.u[7] = f2bf(f1.w);
  *(uint4*)(Abf + i) = t.v;
}

// ---------------------------------------------------------------------------
// GEMM (unchanged from R2): 128x128 tile, BK=32, global_load_lds staging,
// XCD-swizzled grid. Column meaning is opaque to the GEMM.
// ---------------------------------------------------------------------------
__global__ __launch_bounds__(256) void gemm_kernel(const u16* __restrict__ Abf,
                                                   const u16* __restrict__ WcatT,
                                                   const float* __restrict__ bcat,
                                                   u16* __restrict__ G) {
  __shared__ __align__(16) u16 As[4096];
  __shared__ __align__(16) u16 Bs[4096];
  const int tid = threadIdx.x;
  const int lane = tid & 63, wave = tid >> 6;
  const int wm = wave >> 1, wn = wave & 1;
  const int q = lane >> 4, r = lane & 15;

  const int xcd = blockIdx.x & 7;
  const int li  = blockIdx.x >> 3;
  const int mt  = xcd * 64 + li / 12;
  const int nt  = li % 12;
  const int m0 = mt * 128, n0 = nt * 128;

  const int bi0 = wave * 128 + lane;
  const int bi1 = bi0 + 64;
  const u16* gA0 = Abf   + (size_t)(m0 + (bi0 >> 2)) * KDIM + (bi0 & 3) * 8;
  const u16* gA1 = Abf   + (size_t)(m0 + (bi1 >> 2)) * KDIM + (bi1 & 3) * 8;
  const u16* gB0 = WcatT + (size_t)(n0 + (bi0 >> 2)) * KDIM + (bi0 & 3) * 8;
  const u16* gB1 = WcatT + (size_t)(n0 + (bi1 >> 2)) * KDIM + (bi1 & 3) * 8;
  u16* lA0 = As + wave * 1024;
  u16* lA1 = As + wave * 1024 + 512;
  u16* lB0 = Bs + wave * 1024;
  u16* lB1 = Bs + wave * 1024 + 512;

  floatx4 acc[4][4];
  floatx4 z4 = {0.f, 0.f, 0.f, 0.f};
#pragma unroll
  for (int i = 0; i < 4; i++)
#pragma unroll
    for (int j = 0; j < 4; j++) acc[i][j] = z4;

  for (int k0 = 0; k0 < KDIM; k0 += 32) {
    gll16(gA0 + k0, lA0);
    gll16(gA1 + k0, lA1);
    gll16(gB0 + k0, lB0);
    gll16(gB1 + k0, lB1);
    __syncthreads();
    bf16x8 af[4], bv[4];
#pragma unroll
    for (int i = 0; i < 4; i++)
      af[i] = *(const bf16x8*)(As + ((wm * 64 + i * 16 + r) * 4 + q) * 8);
#pragma unroll
    for (int j = 0; j < 4; j++)
      bv[j] = *(const bf16x8*)(Bs + ((wn * 64 + j * 16 + r) * 4 + q) * 8);
#pragma unroll
    for (int i = 0; i < 4; i++)
#pragma unroll
      for (int j = 0; j < 4; j++)
        acc[i][j] = __builtin_amdgcn_mfma_f32_16x16x32_bf16(af[i], bv[j], acc[i][j], 0, 0, 0);
    __syncthreads();
  }

  float bvals[4];
#pragma unroll
  for (int j = 0; j < 4; j++) bvals[j] = bcat[n0 + wn * 64 + j * 16 + r];
#pragma unroll
  for (int i = 0; i < 4; i++) {
#pragma unroll
    for (int reg = 0; reg < 4; reg++) {
      size_t grow = (size_t)(m0 + wm * 64 + i * 16 + q * 4 + reg);
      u16* dst = G + grow * NDIM + n0 + wn * 64 + r;
#pragma unroll
      for (int j = 0; j < 4; j++)
        dst[j * 16] = f2bf(acc[i][j][reg] + bvals[j]);
    }
  }
}

// ---------------------------------------------------------------------------
// Scan phase A: per-chunk affine summary. Unit = 1 wave (64 lanes x 4 d).
// One uint4 load per t gives interleaved (h,z) for 4 d's.
// ---------------------------------------------------------------------------
__global__ __launch_bounds__(256) void scan_phaseA(const u16* __restrict__ G,
                                                   float* __restrict__ Acc,
                                                   float* __restrict__ Bcc) {
  const int slot = threadIdx.x >> 6, lane = threadIdx.x & 63;
  const int u = blockIdx.x * 4 + slot;         // 0..4095
  const int c = u & 255, b = (u >> 8) & 7, dir = u >> 11;
  const u16* p0 = G + (size_t)b * LDIM * NDIM + dir * 768 + lane * 8;
  float h[4], P[4];
#pragma unroll
  for (int e = 0; e < 4; ++e) { h[e] = 0.f; P[e] = 1.f; }
#pragma unroll 4
  for (int i = 0; i < TCH; ++i) {
    const int t = dir ? (c * TCH + (TCH - 1 - i)) : (c * TCH + i);
    uint4 hz = *(const uint4*)(p0 + (size_t)t * NDIM);
    const u16* q = (const u16*)&hz;
#pragma unroll
    for (int e = 0; e < 4; ++e) {
      float z = sigmoidf_fast(bf2f(q[2 * e + 1]));
      float a = 1.f - z;
      h[e] = fmaf(a, h[e], z * bf2f(q[2 * e]));
      P[e] *= a;
    }
  }
  float4 v;
  v.x = P[0]; v.y = P[1]; v.z = P[2]; v.w = P[3];
  *(float4*)(Acc + (size_t)u * 256 + lane * 4) = v;
  v.x = h[0]; v.y = h[1]; v.z = h[2]; v.w = h[3];
  *(float4*)(Bcc + (size_t)u * 256 + lane * 4) = v;
}

// ---------------------------------------------------------------------------
// Scan phase B: chain 256 chunk summaries, 8-deep load batching.
// ---------------------------------------------------------------------------
__global__ void scan_phaseB(const float* __restrict__ Acc, const float* __restrict__ Bcc,
                            const float* __restrict__ h01, const float* __restrict__ h0_1,
                            float* __restrict__ Pref) {
  const int d = threadIdx.x, b = blockIdx.x, dir = blockIdx.y;
  float h = dir ? h0_1[d] : h01[d];
  const size_t ubase = ((size_t)dir * BDIM + b) * NCH;
  if (dir == 0) {
    for (int c0 = 0; c0 < NCH; c0 += 8) {
      float a[8], bb[8];
#pragma unroll
      for (int j = 0; j < 8; ++j) {
        size_t idx = (ubase + c0 + j) * DDIM + d;
        a[j] = Acc[idx]; bb[j] = Bcc[idx];
      }
#pragma unroll
      for (int j = 0; j < 8; ++j) {
        Pref[(ubase + c0 + j) * DDIM + d] = h;
        h = fmaf(a[j], h, bb[j]);
      }
    }
  } else {
    for (int c0 = NCH - 1; c0 >= 0; c0 -= 8) {
      float a[8], bb[8];
#pragma unroll
      for (int j = 0; j < 8; ++j) {
        size_t idx = (ubase + c0 - j) * DDIM + d;
        a[j] = Acc[idx]; bb[j] = Bcc[idx];
      }
#pragma unroll
      for (int j = 0; j < 8; ++j) {
        Pref[(ubase + c0 - j) * DDIM + d] = h;
        h = fmaf(a[j], h, bb[j]);
      }
    }
  }
}

// ---------------------------------------------------------------------------
// Scan phase C fwd: replay with prefix, out = h * sigmoid(gs). Wave-unit.
// ---------------------------------------------------------------------------
__global__ __launch_bounds__(256) void scan_phaseC_fwd(const u16* __restrict__ G,
                                                       const float* __restrict__ Pref,
                                                       float* __restrict__ out) {
  const int slot = threadIdx.x >> 6, lane = threadIdx.x & 63;
  const int u = blockIdx.x * 4 + slot;         // 0..2047
  const int c = u & 255, b = u >> 8;
  float4 p0 = *(const float4*)(Pref + (size_t)u * 256 + lane * 4);
  float h[4] = {p0.x, p0.y, p0.z, p0.w};
  const u16* ghz = G + (size_t)b * LDIM * NDIM + lane * 8;
  const u16* gs  = G + (size_t)b * LDIM * NDIM + 512 + lane * 4;
  float* o0 = out + (size_t)b * LDIM * DDIM + lane * 4;
#pragma unroll 4
  for (int i = 0; i < TCH; ++i) {
    const int t = c * TCH + i;
    uint4 hz = *(const uint4*)(ghz + (size_t)t * NDIM);
    uint2 sv = *(const uint2*)(gs + (size_t)t * NDIM);
    const u16* q = (const u16*)&hz;
    const u16* sq = (const u16*)&sv;
    float4 v;
    float* o = (float*)&v;
#pragma unroll
    for (int e = 0; e < 4; ++e) {
      float z = sigmoidf_fast(bf2f(q[2 * e + 1]));
      h[e] = fmaf(1.f - z, h[e], z * bf2f(q[2 * e]));
      o[e] = h[e] * sigmoidf_fast(bf2f(sq[e]));
    }
    *(float4*)(o0 + (size_t)t * DDIM) = v;
  }
}

// ---------------------------------------------------------------------------
// Scan phase C bwd: descending replay, out += h * sigmoid(gs).
// ---------------------------------------------------------------------------
__global__ __launch_bounds__(256) void scan_phaseC_bwd(const u16* __restrict__ G,
                                                       const float* __restrict__ Pref,
                                                       float* __restrict__ out) {
  const int slot = threadIdx.x >> 6, lane = threadIdx.x & 63;
  const int u = blockIdx.x * 4 + slot;         // 0..2047
  const int c = u & 255, b = u >> 8;
  float4 p0 = *(const float4*)(Pref + (size_t)(2048 + u) * 256 + lane * 4);
  float h[4] = {p0.x, p0.y, p0.z, p0.w};
  const u16* ghz = G + (size_t)b * LDIM * NDIM + 768 + lane * 8;
  const u16* gs  = G + (size_t)b * LDIM * NDIM + 1280 + lane * 4;
  float* o0 = out + (size_t)b * LDIM * DDIM + lane * 4;
#pragma unroll 4
  for (int i = 0; i < TCH; ++i) {
    const int t = c * TCH + (TCH - 1 - i);
    uint4 hz = *(const uint4*)(ghz + (size_t)t * NDIM);
    uint2 sv = *(const uint2*)(gs + (size_t)t * NDIM);
    const u16* q = (const u16*)&hz;
    const u16* sq = (const u16*)&sv;
    float* op = o0 + (size_t)t * DDIM;
    float4 cur = *(const float4*)op;
    float* o = (float*)&cur;
#pragma unroll
    for (int e = 0; e < 4; ++e) {
      float z = sigmoidf_fast(bf2f(q[2 * e + 1]));
      h[e] = fmaf(1.f - z, h[e], z * bf2f(q[2 * e]));
      o[e] += h[e] * sigmoidf_fast(bf2f(sq[e]));
    }
    *(float4*)op = cur;
  }
}

extern "C" void kernel_launch(void* const* d_in, const int* in_sizes, int n_in,
                              void* d_out, int out_size, void* d_ws, size_t ws_size,
                              hipStream_t stream) {
  const float* xs   = (const float*)d_in[0];
  const float* Wh1  = (const float*)d_in[1];
  const float* bh1  = (const float*)d_in[2];
  const float* Wz1  = (const float*)d_in[3];
  const float* bz1  = (const float*)d_in[4];
  const float* Ws1  = (const float*)d_in[5];
  const float* bs1  = (const float*)d_in[6];
  const float* h01  = (const float*)d_in[7];
  const float* Wh_1 = (const float*)d_in[8];
  const float* bh_1 = (const float*)d_in[9];
  const float* Wz_1 = (const float*)d_in[10];
  const float* bz_1 = (const float*)d_in[11];
  const float* Ws_1 = (const float*)d_in[12];
  const float* bs_1 = (const float*)d_in[13];
  const float* h0_1 = (const float*)d_in[14];
  float* out = (float*)d_out;

  char* ws = (char*)d_ws;
  u16* WcatT = (u16*)ws;   ws += (size_t)NDIM * KDIM * 2;   // 0.75 MB
  float* bcat = (float*)ws; ws += (size_t)NDIM * 4;         // 6 KB
  u16* Abf = (u16*)ws;     ws += (size_t)MTOT * KDIM * 2;   // 32 MB
  u16* G = (u16*)ws;       ws += (size_t)MTOT * NDIM * 2;   // 192 MB
  // Summary arrays alias Abf (dead after gemm). 12 MB <= 32 MB.
  float* Acc  = (float*)Abf;
  float* Bcc  = Acc + (size_t)2 * BDIM * NCH * DDIM;
  float* Pref = Bcc + (size_t)2 * BDIM * NCH * DDIM;
  if ((size_t)(ws - (char*)d_ws) > ws_size) return;

  prep_weights<<<dim3(NDIM), dim3(KDIM), 0, stream>>>(
      Wh1, Wz1, Ws1, Wh_1, Wz_1, Ws_1, bh1, bz1, bs1, bh_1, bz_1, bs_1, WcatT, bcat);
  convert_xs<<<dim3(MTOT * KDIM / (256 * 8)), dim3(256), 0, stream>>>(xs, Abf);
  gemm_kernel<<<dim3(6144), dim3(256), 0, stream>>>(Abf, WcatT, bcat, G);
  scan_phaseA<<<dim3(1024), dim3(256), 0, stream>>>(G, Acc, Bcc);
  scan_phaseB<<<dim3(BDIM, 2), dim3(DDIM), 0, stream>>>(Acc, Bcc, h01, h0_1, Pref);
  scan_phaseC_fwd<<<dim3(512), dim3(256), 0, stream>>>(G, Pref, out);
  scan_phaseC_bwd<<<dim3(512), dim3(256), 0, stream>>>(G, Pref, out);
}

// Round 4
// 299.205 us; speedup vs baseline: 1.1988x; 1.0915x over previous
//
#include <hip/hip_runtime.h>
#include <hip/hip_bf16.h>

typedef unsigned short u16;

#define BDIM 8
#define LDIM 8192
#define KDIM 256      // C
#define DDIM 256      // D
#define MTOT 65536    // B*L
#define NDIM 1536     // 6*D
#define TCH  32       // scan chunk length
#define NCH  256      // chunks per sequence

// Physical column layout of G (per m-row), dir f in {0,1}, base = f*768:
//   [base + 2d + 0] = h-gate col d   [base + 2d + 1] = z-gate col d  (d<256)
//   [base + 512 + d] = s-gate col d

typedef float floatx4 __attribute__((ext_vector_type(4)));
typedef short bf16x8 __attribute__((ext_vector_type(8)));

__device__ __forceinline__ u16 f2bf(float f) {
  union { __hip_bfloat16 h; u16 u; } c;
  c.h = __float2bfloat16(f);
  return c.u;
}
__device__ __forceinline__ float bf2f(u16 u) {
  union { unsigned int i; float f; } c;
  c.i = ((unsigned int)u) << 16;
  return c.f;
}
__device__ __forceinline__ float sigmoidf_fast(float x) {
  return __builtin_amdgcn_rcpf(1.0f + __expf(-x));
}
__device__ __forceinline__ void gll16(const u16* g, u16* l) {
  __builtin_amdgcn_global_load_lds((const __attribute__((address_space(1))) void*)g,
                                   (__attribute__((address_space(3))) void*)l, 16, 0, 0);
}

// ---------------------------------------------------------------------------
// Prep: WcatT[n][k] = W(n)[k][d(n)] bf16 with the interleaved physical layout.
// ---------------------------------------------------------------------------
__global__ void prep_weights(const float* __restrict__ Wh1, const float* __restrict__ Wz1,
                             const float* __restrict__ Ws1, const float* __restrict__ Wh_1,
                             const float* __restrict__ Wz_1, const float* __restrict__ Ws_1,
                             const float* __restrict__ bh1, const float* __restrict__ bz1,
                             const float* __restrict__ bs1, const float* __restrict__ bh_1,
                             const float* __restrict__ bz_1, const float* __restrict__ bs_1,
                             u16* __restrict__ WcatT, float* __restrict__ bcat) {
  const int n = blockIdx.x;       // physical col 0..1535
  const int k = threadIdx.x;      // 0..255
  const int dir = n / 768, r = n % 768;
  int d; const float* W; const float* bb;
  if (r < 512) {
    d = r >> 1;
    if (r & 1) { W = dir ? Wz_1 : Wz1; bb = dir ? bz_1 : bz1; }
    else       { W = dir ? Wh_1 : Wh1; bb = dir ? bh_1 : bh1; }
  } else {
    d = r - 512;
    W = dir ? Ws_1 : Ws1; bb = dir ? bs_1 : bs1;
  }
  WcatT[(size_t)n * KDIM + k] = f2bf(W[k * DDIM + d]);
  if (k == 0) bcat[n] = bb[d];
}

// ---------------------------------------------------------------------------
// Convert xs fp32 -> bf16
// ---------------------------------------------------------------------------
__global__ void convert_xs(const float* __restrict__ xs, u16* __restrict__ Abf) {
  size_t i = ((size_t)blockIdx.x * 256 + threadIdx.x) * 8;
  const float4* s = (const float4*)(xs + i);
  float4 f0 = s[0], f1 = s[1];
  union { u16 u[8]; uint4 v; } t;
  t.u[0] = f2bf(f0.x); t.u[1] = f2bf(f0.y); t.u[2] = f2bf(f0.z); t.u[3] = f2bf(f0.w);
  t.u[4] = f2bf(f1.x); t.u[5] = f2bf(f1.y); t.u[6] = f2bf(f1.z); t.u[7] = f2bf(f1.w);
  *(uint4*)(Abf + i) = t.v;
}

// ---------------------------------------------------------------------------
// GEMM: 128x128 tile, BK=64 (8 barriers total), global_load_lds staging,
// XCD-swizzled grid. 32 MFMA per barrier pair.
// ---------------------------------------------------------------------------
__global__ __launch_bounds__(256) void gemm_kernel(const u16* __restrict__ Abf,
                                                   const u16* __restrict__ WcatT,
                                                   const float* __restrict__ bcat,
                                                   u16* __restrict__ G) {
  __shared__ __align__(16) u16 As[8192];   // 128 rows x 64 k
  __shared__ __align__(16) u16 Bs[8192];
  const int tid = threadIdx.x;
  const int lane = tid & 63, wave = tid >> 6;
  const int wm = wave >> 1, wn = wave & 1;
  const int q = lane >> 4, r = lane & 15;

  const int xcd = blockIdx.x & 7;
  const int li  = blockIdx.x >> 3;
  const int mt  = xcd * 64 + li / 12;
  const int nt  = li % 12;
  const int m0 = mt * 128, n0 = nt * 128;

  const u16* gA[4]; const u16* gB[4]; u16* lA[4]; u16* lB[4];
#pragma unroll
  for (int j = 0; j < 4; j++) {
    const int bi = wave * 256 + j * 64 + lane;   // 16B-block idx, row = bi>>3, kq = bi&7
    gA[j] = Abf   + (size_t)(m0 + (bi >> 3)) * KDIM + (bi & 7) * 8;
    gB[j] = WcatT + (size_t)(n0 + (bi >> 3)) * KDIM + (bi & 7) * 8;
    lA[j] = As + bi * 8;
    lB[j] = Bs + bi * 8;
  }

  floatx4 acc[4][4];
  floatx4 z4 = {0.f, 0.f, 0.f, 0.f};
#pragma unroll
  for (int i = 0; i < 4; i++)
#pragma unroll
    for (int j = 0; j < 4; j++) acc[i][j] = z4;

  for (int k0 = 0; k0 < KDIM; k0 += 64) {
#pragma unroll
    for (int j = 0; j < 4; j++) { gll16(gA[j] + k0, lA[j]); gll16(gB[j] + k0, lB[j]); }
    __syncthreads();
#pragma unroll
    for (int kk = 0; kk < 2; kk++) {
      bf16x8 af[4], bv[4];
#pragma unroll
      for (int i = 0; i < 4; i++)
        af[i] = *(const bf16x8*)(As + ((wm * 64 + i * 16 + r) * 8 + kk * 4 + q) * 8);
#pragma unroll
      for (int j = 0; j < 4; j++)
        bv[j] = *(const bf16x8*)(Bs + ((wn * 64 + j * 16 + r) * 8 + kk * 4 + q) * 8);
#pragma unroll
      for (int i = 0; i < 4; i++)
#pragma unroll
        for (int j = 0; j < 4; j++)
          acc[i][j] = __builtin_amdgcn_mfma_f32_16x16x32_bf16(af[i], bv[j], acc[i][j], 0, 0, 0);
    }
    __syncthreads();
  }

  // C/D layout: col = lane&15, row = (lane>>4)*4 + reg  [m89/m91]
  float bvals[4];
#pragma unroll
  for (int j = 0; j < 4; j++) bvals[j] = bcat[n0 + wn * 64 + j * 16 + r];
#pragma unroll
  for (int i = 0; i < 4; i++) {
#pragma unroll
    for (int reg = 0; reg < 4; reg++) {
      size_t grow = (size_t)(m0 + wm * 64 + i * 16 + q * 4 + reg);
      u16* dst = G + grow * NDIM + n0 + wn * 64 + r;
#pragma unroll
      for (int j = 0; j < 4; j++)
        dst[j * 16] = f2bf(acc[i][j][reg] + bvals[j]);
    }
  }
}

// ---------------------------------------------------------------------------
// Scan phase A: per-chunk affine summary. 2 waves per unit, 2 d/lane.
// ---------------------------------------------------------------------------
__global__ __launch_bounds__(256) void scan_phaseA(const u16* __restrict__ G,
                                                   float* __restrict__ Acc,
                                                   float* __restrict__ Bcc) {
  const int slot = threadIdx.x >> 6, lane = threadIdx.x & 63;
  const int w = blockIdx.x * 4 + slot;          // 0..8191
  const int u = w >> 1, half = w & 1;           // unit 0..4095
  const int c = u & 255, b = (u >> 8) & 7, dir = u >> 11;
  const int d0 = half * 128 + lane * 2;
  const u16* p0 = G + (size_t)b * LDIM * NDIM + dir * 768 + d0 * 2;
  float h0 = 0.f, h1 = 0.f, P0 = 1.f, P1 = 1.f;
#pragma unroll 4
  for (int i = 0; i < TCH; ++i) {
    const int t = dir ? (c * TCH + (TCH - 1 - i)) : (c * TCH + i);
    uint2 hz = *(const uint2*)(p0 + (size_t)t * NDIM);
    const u16* q = (const u16*)&hz;
    float z0 = sigmoidf_fast(bf2f(q[1]));
    float z1 = sigmoidf_fast(bf2f(q[3]));
    float a0 = 1.f - z0, a1 = 1.f - z1;
    h0 = fmaf(a0, h0, z0 * bf2f(q[0]));
    h1 = fmaf(a1, h1, z1 * bf2f(q[2]));
    P0 *= a0; P1 *= a1;
  }
  float2 v;
  v.x = P0; v.y = P1;
  *(float2*)(Acc + (size_t)u * 256 + d0) = v;
  v.x = h0; v.y = h1;
  *(float2*)(Bcc + (size_t)u * 256 + d0) = v;
}

// ---------------------------------------------------------------------------
// Scan phase B: chain 256 chunk summaries, 8-deep load batching.
// ---------------------------------------------------------------------------
__global__ void scan_phaseB(const float* __restrict__ Acc, const float* __restrict__ Bcc,
                            const float* __restrict__ h01, const float* __restrict__ h0_1,
                            float* __restrict__ Pref) {
  const int d = threadIdx.x, b = blockIdx.x, dir = blockIdx.y;
  float h = dir ? h0_1[d] : h01[d];
  const size_t ubase = ((size_t)dir * BDIM + b) * NCH;
  if (dir == 0) {
    for (int c0 = 0; c0 < NCH; c0 += 8) {
      float a[8], bb[8];
#pragma unroll
      for (int j = 0; j < 8; ++j) {
        size_t idx = (ubase + c0 + j) * DDIM + d;
        a[j] = Acc[idx]; bb[j] = Bcc[idx];
      }
#pragma unroll
      for (int j = 0; j < 8; ++j) {
        Pref[(ubase + c0 + j) * DDIM + d] = h;
        h = fmaf(a[j], h, bb[j]);
      }
    }
  } else {
    for (int c0 = NCH - 1; c0 >= 0; c0 -= 8) {
      float a[8], bb[8];
#pragma unroll
      for (int j = 0; j < 8; ++j) {
        size_t idx = (ubase + c0 - j) * DDIM + d;
        a[j] = Acc[idx]; bb[j] = Bcc[idx];
      }
#pragma unroll
      for (int j = 0; j < 8; ++j) {
        Pref[(ubase + c0 - j) * DDIM + d] = h;
        h = fmaf(a[j], h, bb[j]);
      }
    }
  }
}

// ---------------------------------------------------------------------------
// Scan phase C (fused fwd+bwd): block = one (b,c) chunk.
// Waves 2,3 (bwd): descending replay, hb*sb -> LDS.
// Barrier. Waves 0,1 (fwd): ascending replay, out = hf*sf + LDS. One write.
// ---------------------------------------------------------------------------
__global__ __launch_bounds__(256) void scan_phaseC(const u16* __restrict__ G,
                                                   const float* __restrict__ Pref,
                                                   float* __restrict__ out) {
  __shared__ float obuf[TCH * 256];   // 32 KB
  const int c = blockIdx.x & 255, b = blockIdx.x >> 8;
  const int wave = threadIdx.x >> 6, lane = threadIdx.x & 63;
  const int dir = wave >> 1, half = wave & 1;
  const int d0 = half * 128 + lane * 2;
  const int u = dir * 2048 + b * 256 + c;
  float h0 = Pref[(size_t)u * 256 + d0];
  float h1 = Pref[(size_t)u * 256 + d0 + 1];
  const u16* ghz = G + (size_t)b * LDIM * NDIM + dir * 768 + d0 * 2;
  const u16* gs  = G + (size_t)b * LDIM * NDIM + dir * 768 + 512 + d0;

  if (dir == 1) {
#pragma unroll 4
    for (int i = 0; i < TCH; ++i) {
      const int tl = TCH - 1 - i;
      const int t = c * TCH + tl;
      uint2 hz = *(const uint2*)(ghz + (size_t)t * NDIM);
      unsigned int sv = *(const unsigned int*)(gs + (size_t)t * NDIM);
      const u16* q = (const u16*)&hz;
      const u16* sq = (const u16*)&sv;
      float z0 = sigmoidf_fast(bf2f(q[1]));
      float z1 = sigmoidf_fast(bf2f(q[3]));
      h0 = fmaf(1.f - z0, h0, z0 * bf2f(q[0]));
      h1 = fmaf(1.f - z1, h1, z1 * bf2f(q[2]));
      float2 o;
      o.x = h0 * sigmoidf_fast(bf2f(sq[0]));
      o.y = h1 * sigmoidf_fast(bf2f(sq[1]));
      *(float2*)(obuf + tl * 256 + d0) = o;
    }
  }
  __syncthreads();
  if (dir == 0) {
#pragma unroll 4
    for (int i = 0; i < TCH; ++i) {
      const int t = c * TCH + i;
      uint2 hz = *(const uint2*)(ghz + (size_t)t * NDIM);
      unsigned int sv = *(const unsigned int*)(gs + (size_t)t * NDIM);
      const u16* q = (const u16*)&hz;
      const u16* sq = (const u16*)&sv;
      float z0 = sigmoidf_fast(bf2f(q[1]));
      float z1 = sigmoidf_fast(bf2f(q[3]));
      h0 = fmaf(1.f - z0, h0, z0 * bf2f(q[0]));
      h1 = fmaf(1.f - z1, h1, z1 * bf2f(q[2]));
      float2 bb = *(const float2*)(obuf + i * 256 + d0);
      float2 o;
      o.x = fmaf(h0, sigmoidf_fast(bf2f(sq[0])), bb.x);
      o.y = fmaf(h1, sigmoidf_fast(bf2f(sq[1])), bb.y);
      *(float2*)(out + ((size_t)b * LDIM + t) * DDIM + d0) = o;
    }
  }
}

extern "C" void kernel_launch(void* const* d_in, const int* in_sizes, int n_in,
                              void* d_out, int out_size, void* d_ws, size_t ws_size,
                              hipStream_t stream) {
  const float* xs   = (const float*)d_in[0];
  const float* Wh1  = (const float*)d_in[1];
  const float* bh1  = (const float*)d_in[2];
  const float* Wz1  = (const float*)d_in[3];
  const float* bz1  = (const float*)d_in[4];
  const float* Ws1  = (const float*)d_in[5];
  const float* bs1  = (const float*)d_in[6];
  const float* h01  = (const float*)d_in[7];
  const float* Wh_1 = (const float*)d_in[8];
  const float* bh_1 = (const float*)d_in[9];
  const float* Wz_1 = (const float*)d_in[10];
  const float* bz_1 = (const float*)d_in[11];
  const float* Ws_1 = (const float*)d_in[12];
  const float* bs_1 = (const float*)d_in[13];
  const float* h0_1 = (const float*)d_in[14];
  float* out = (float*)d_out;

  char* ws = (char*)d_ws;
  u16* WcatT = (u16*)ws;   ws += (size_t)NDIM * KDIM * 2;   // 0.75 MB
  float* bcat = (float*)ws; ws += (size_t)NDIM * 4;         // 6 KB
  u16* Abf = (u16*)ws;     ws += (size_t)MTOT * KDIM * 2;   // 32 MB
  u16* G = (u16*)ws;       ws += (size_t)MTOT * NDIM * 2;   // 192 MB
  // Summary arrays alias Abf (dead after gemm). 12 MB <= 32 MB.
  float* Acc  = (float*)Abf;
  float* Bcc  = Acc + (size_t)2 * BDIM * NCH * DDIM;
  float* Pref = Bcc + (size_t)2 * BDIM * NCH * DDIM;
  if ((size_t)(ws - (char*)d_ws) > ws_size) return;

  prep_weights<<<dim3(NDIM), dim3(KDIM), 0, stream>>>(
      Wh1, Wz1, Ws1, Wh_1, Wz_1, Ws_1, bh1, bz1, bs1, bh_1, bz_1, bs_1, WcatT, bcat);
  convert_xs<<<dim3(MTOT * KDIM / (256 * 8)), dim3(256), 0, stream>>>(xs, Abf);
  gemm_kernel<<<dim3(6144), dim3(256), 0, stream>>>(Abf, WcatT, bcat, G);
  scan_phaseA<<<dim3(2048), dim3(256), 0, stream>>>(G, Acc, Bcc);
  scan_phaseB<<<dim3(BDIM, 2), dim3(DDIM), 0, stream>>>(Acc, Bcc, h01, h0_1, Pref);
  scan_phaseC<<<dim3(2048), dim3(256), 0, stream>>>(G, Pref, out);
}

// Round 5
// 293.386 us; speedup vs baseline: 1.2226x; 1.0198x over previous
//
#include <hip/hip_runtime.h>
#include <hip/hip_bf16.h>

typedef unsigned short u16;

#define BDIM 8
#define LDIM 8192
#define KDIM 256      // C
#define DDIM 256      // D
#define MTOT 65536    // B*L
#define NDIM 1536     // 6*D
#define TCH  32       // scan chunk length
#define NCH  256      // chunks per sequence

// Physical column layout of G (per m-row), dir f in {0,1}, base = f*768:
//   [base + 2d + 0] = h-gate col d   [base + 2d + 1] = z-gate col d  (d<256)
//   [base + 512 + d] = s-gate col d

typedef float floatx4 __attribute__((ext_vector_type(4)));
typedef short bf16x8 __attribute__((ext_vector_type(8)));

__device__ __forceinline__ u16 f2bf(float f) {
  union { __hip_bfloat16 h; u16 u; } c;
  c.h = __float2bfloat16(f);
  return c.u;
}
__device__ __forceinline__ float bf2f(u16 u) {
  union { unsigned int i; float f; } c;
  c.i = ((unsigned int)u) << 16;
  return c.f;
}
__device__ __forceinline__ float sigmoidf_fast(float x) {
  return __builtin_amdgcn_rcpf(1.0f + __expf(-x));
}
__device__ __forceinline__ void gll16(const u16* g, u16* l) {
  __builtin_amdgcn_global_load_lds((const __attribute__((address_space(1))) void*)g,
                                   (__attribute__((address_space(3))) void*)l, 16, 0, 0);
}

// ---------------------------------------------------------------------------
// Prep: WcatT[n][k] = W(n)[k][d(n)] bf16 with the interleaved physical layout.
// ---------------------------------------------------------------------------
__global__ void prep_weights(const float* __restrict__ Wh1, const float* __restrict__ Wz1,
                             const float* __restrict__ Ws1, const float* __restrict__ Wh_1,
                             const float* __restrict__ Wz_1, const float* __restrict__ Ws_1,
                             const float* __restrict__ bh1, const float* __restrict__ bz1,
                             const float* __restrict__ bs1, const float* __restrict__ bh_1,
                             const float* __restrict__ bz_1, const float* __restrict__ bs_1,
                             u16* __restrict__ WcatT, float* __restrict__ bcat) {
  const int n = blockIdx.x;       // physical col 0..1535
  const int k = threadIdx.x;      // 0..255
  const int dir = n / 768, r = n % 768;
  int d; const float* W; const float* bb;
  if (r < 512) {
    d = r >> 1;
    if (r & 1) { W = dir ? Wz_1 : Wz1; bb = dir ? bz_1 : bz1; }
    else       { W = dir ? Wh_1 : Wh1; bb = dir ? bh_1 : bh1; }
  } else {
    d = r - 512;
    W = dir ? Ws_1 : Ws1; bb = dir ? bs_1 : bs1;
  }
  WcatT[(size_t)n * KDIM + k] = f2bf(W[k * DDIM + d]);
  if (k == 0) bcat[n] = bb[d];
}

// ---------------------------------------------------------------------------
// Convert xs fp32 -> bf16
// ---------------------------------------------------------------------------
__global__ void convert_xs(const float* __restrict__ xs, u16* __restrict__ Abf) {
  size_t i = ((size_t)blockIdx.x * 256 + threadIdx.x) * 8;
  const float4* s = (const float4*)(xs + i);
  float4 f0 = s[0], f1 = s[1];
  union { u16 u[8]; uint4 v; } t;
  t.u[0] = f2bf(f0.x); t.u[1] = f2bf(f0.y); t.u[2] = f2bf(f0.z); t.u[3] = f2bf(f0.w);
  t.u[4] = f2bf(f1.x); t.u[5] = f2bf(f1.y); t.u[6] = f2bf(f1.z); t.u[7] = f2bf(f1.w);
  *(uint4*)(Abf + i) = t.v;
}

// ---------------------------------------------------------------------------
// GEMM: 128x128 tile, BK=64, global_load_lds staging, XCD-swizzled grid.
// LDS XOR swizzle: physical plane slot s at row r holds logical k-block
// s ^ (r&7). Applied on the per-lane GLOBAL address at staging (LDS dest must
// stay uniform-base + lane*16) and on the plane index at read. Consecutive
// rows rotate through all 8 bank groups -> 2-way max aliasing (free, m136).
// ---------------------------------------------------------------------------
__global__ __launch_bounds__(256) void gemm_kernel(const u16* __restrict__ Abf,
                                                   const u16* __restrict__ WcatT,
                                                   const float* __restrict__ bcat,
                                                   u16* __restrict__ G) {
  __shared__ __align__(16) u16 As[8192];   // 128 rows x 64 k
  __shared__ __align__(16) u16 Bs[8192];
  const int tid = threadIdx.x;
  const int lane = tid & 63, wave = tid >> 6;
  const int wm = wave >> 1, wn = wave & 1;
  const int q = lane >> 4, r = lane & 15;

  const int xcd = blockIdx.x & 7;
  const int li  = blockIdx.x >> 3;
  const int mt  = xcd * 64 + li / 12;
  const int nt  = li % 12;
  const int m0 = mt * 128, n0 = nt * 128;

  const u16* gA[4]; const u16* gB[4]; u16* lA[4]; u16* lB[4];
#pragma unroll
  for (int j = 0; j < 4; j++) {
    const int bi = wave * 256 + j * 64 + lane;   // LDS 16B-slot idx
    const int row = bi >> 3;
    const int kq = (bi & 7) ^ (row & 7);         // logical k-block for this slot
    gA[j] = Abf   + (size_t)(m0 + row) * KDIM + kq * 8;
    gB[j] = WcatT + (size_t)(n0 + row) * KDIM + kq * 8;
    lA[j] = As + bi * 8;
    lB[j] = Bs + bi * 8;
  }

  floatx4 acc[4][4];
  floatx4 z4 = {0.f, 0.f, 0.f, 0.f};
#pragma unroll
  for (int i = 0; i < 4; i++)
#pragma unroll
    for (int j = 0; j < 4; j++) acc[i][j] = z4;

  for (int k0 = 0; k0 < KDIM; k0 += 64) {
#pragma unroll
    for (int j = 0; j < 4; j++) { gll16(gA[j] + k0, lA[j]); gll16(gB[j] + k0, lB[j]); }
    __syncthreads();
#pragma unroll
    for (int kk = 0; kk < 2; kk++) {
      bf16x8 af[4], bv[4];
#pragma unroll
      for (int i = 0; i < 4; i++) {
        const int row = wm * 64 + i * 16 + r;
        af[i] = *(const bf16x8*)(As + (row * 8 + ((kk * 4 + q) ^ (row & 7))) * 8);
      }
#pragma unroll
      for (int j = 0; j < 4; j++) {
        const int row = wn * 64 + j * 16 + r;
        bv[j] = *(const bf16x8*)(Bs + (row * 8 + ((kk * 4 + q) ^ (row & 7))) * 8);
      }
#pragma unroll
      for (int i = 0; i < 4; i++)
#pragma unroll
        for (int j = 0; j < 4; j++)
          acc[i][j] = __builtin_amdgcn_mfma_f32_16x16x32_bf16(af[i], bv[j], acc[i][j], 0, 0, 0);
    }
    __syncthreads();
  }

  // C/D layout: col = lane&15, row = (lane>>4)*4 + reg  [m89/m91]
  float bvals[4];
#pragma unroll
  for (int j = 0; j < 4; j++) bvals[j] = bcat[n0 + wn * 64 + j * 16 + r];
#pragma unroll
  for (int i = 0; i < 4; i++) {
#pragma unroll
    for (int reg = 0; reg < 4; reg++) {
      size_t grow = (size_t)(m0 + wm * 64 + i * 16 + q * 4 + reg);
      u16* dst = G + grow * NDIM + n0 + wn * 64 + r;
#pragma unroll
      for (int j = 0; j < 4; j++)
        dst[j * 16] = f2bf(acc[i][j][reg] + bvals[j]);
    }
  }
}

// ---------------------------------------------------------------------------
// Scan phase A: per-chunk affine summary. 2 waves per unit, 2 d/lane.
// ---------------------------------------------------------------------------
__global__ __launch_bounds__(256) void scan_phaseA(const u16* __restrict__ G,
                                                   float* __restrict__ Acc,
                                                   float* __restrict__ Bcc) {
  const int slot = threadIdx.x >> 6, lane = threadIdx.x & 63;
  const int w = blockIdx.x * 4 + slot;          // 0..8191
  const int u = w >> 1, half = w & 1;           // unit 0..4095
  const int c = u & 255, b = (u >> 8) & 7, dir = u >> 11;
  const int d0 = half * 128 + lane * 2;
  const u16* p0 = G + (size_t)b * LDIM * NDIM + dir * 768 + d0 * 2;
  float h0 = 0.f, h1 = 0.f, P0 = 1.f, P1 = 1.f;
#pragma unroll 4
  for (int i = 0; i < TCH; ++i) {
    const int t = dir ? (c * TCH + (TCH - 1 - i)) : (c * TCH + i);
    uint2 hz = *(const uint2*)(p0 + (size_t)t * NDIM);
    const u16* q = (const u16*)&hz;
    float z0 = sigmoidf_fast(bf2f(q[1]));
    float z1 = sigmoidf_fast(bf2f(q[3]));
    float a0 = 1.f - z0, a1 = 1.f - z1;
    h0 = fmaf(a0, h0, z0 * bf2f(q[0]));
    h1 = fmaf(a1, h1, z1 * bf2f(q[2]));
    P0 *= a0; P1 *= a1;
  }
  float2 v;
  v.x = P0; v.y = P1;
  *(float2*)(Acc + (size_t)u * 256 + d0) = v;
  v.x = h0; v.y = h1;
  *(float2*)(Bcc + (size_t)u * 256 + d0) = v;
}

// ---------------------------------------------------------------------------
// Scan phase B: chain 256 chunk summaries, 8-deep load batching.
// ---------------------------------------------------------------------------
__global__ void scan_phaseB(const float* __restrict__ Acc, const float* __restrict__ Bcc,
                            const float* __restrict__ h01, const float* __restrict__ h0_1,
                            float* __restrict__ Pref) {
  const int d = threadIdx.x, b = blockIdx.x, dir = blockIdx.y;
  float h = dir ? h0_1[d] : h01[d];
  const size_t ubase = ((size_t)dir * BDIM + b) * NCH;
  if (dir == 0) {
    for (int c0 = 0; c0 < NCH; c0 += 8) {
      float a[8], bb[8];
#pragma unroll
      for (int j = 0; j < 8; ++j) {
        size_t idx = (ubase + c0 + j) * DDIM + d;
        a[j] = Acc[idx]; bb[j] = Bcc[idx];
      }
#pragma unroll
      for (int j = 0; j < 8; ++j) {
        Pref[(ubase + c0 + j) * DDIM + d] = h;
        h = fmaf(a[j], h, bb[j]);
      }
    }
  } else {
    for (int c0 = NCH - 1; c0 >= 0; c0 -= 8) {
      float a[8], bb[8];
#pragma unroll
      for (int j = 0; j < 8; ++j) {
        size_t idx = (ubase + c0 - j) * DDIM + d;
        a[j] = Acc[idx]; bb[j] = Bcc[idx];
      }
#pragma unroll
      for (int j = 0; j < 8; ++j) {
        Pref[(ubase + c0 - j) * DDIM + d] = h;
        h = fmaf(a[j], h, bb[j]);
      }
    }
  }
}

// ---------------------------------------------------------------------------
// Scan phase C (fused, concurrent dirs): block = one (b,c) chunk, 512 thr.
// Waves 4..7 (bwd) and 0..3 (fwd) compute their chains SIMULTANEOUSLY;
// bwd stores hb*sb to LDS, fwd keeps hf*sf in regs (fully unrolled);
// one barrier; fwd merges and writes out. 1 d per lane.
// ---------------------------------------------------------------------------
__global__ __launch_bounds__(512) void scan_phaseC(const u16* __restrict__ G,
                                                   const float* __restrict__ Pref,
                                                   float* __restrict__ out) {
  __shared__ float obuf[TCH * 256];   // 32 KB
  const int c = blockIdx.x & 255, b = blockIdx.x >> 8;
  const int wave = threadIdx.x >> 6, lane = threadIdx.x & 63;
  const int dir = wave >> 2;
  const int d0 = (wave & 3) * 64 + lane;
  const int u = dir * 2048 + b * 256 + c;
  float h = Pref[(size_t)u * 256 + d0];
  const u16* ghz = G + (size_t)b * LDIM * NDIM + dir * 768 + d0 * 2;
  const u16* gs  = G + (size_t)b * LDIM * NDIM + dir * 768 + 512 + d0;

  if (dir == 1) {
#pragma unroll
    for (int i = 0; i < TCH; ++i) {
      const int tl = TCH - 1 - i;
      const int t = c * TCH + tl;
      unsigned int hz = *(const unsigned int*)(ghz + (size_t)t * NDIM);
      u16 sv = gs[(size_t)t * NDIM];
      float z = sigmoidf_fast(bf2f((u16)(hz >> 16)));
      h = fmaf(1.f - z, h, z * bf2f((u16)(hz & 0xffff)));
      obuf[tl * 256 + d0] = h * sigmoidf_fast(bf2f(sv));
    }
    __syncthreads();
  } else {
    float ov[TCH];
#pragma unroll
    for (int i = 0; i < TCH; ++i) {
      const int t = c * TCH + i;
      unsigned int hz = *(const unsigned int*)(ghz + (size_t)t * NDIM);
      u16 sv = gs[(size_t)t * NDIM];
      float z = sigmoidf_fast(bf2f((u16)(hz >> 16)));
      h = fmaf(1.f - z, h, z * bf2f((u16)(hz & 0xffff)));
      ov[i] = h * sigmoidf_fast(bf2f(sv));
    }
    __syncthreads();
#pragma unroll
    for (int i = 0; i < TCH; ++i) {
      const int t = c * TCH + i;
      out[((size_t)b * LDIM + t) * DDIM + d0] = ov[i] + obuf[i * 256 + d0];
    }
  }
}

extern "C" void kernel_launch(void* const* d_in, const int* in_sizes, int n_in,
                              void* d_out, int out_size, void* d_ws, size_t ws_size,
                              hipStream_t stream) {
  const float* xs   = (const float*)d_in[0];
  const float* Wh1  = (const float*)d_in[1];
  const float* bh1  = (const float*)d_in[2];
  const float* Wz1  = (const float*)d_in[3];
  const float* bz1  = (const float*)d_in[4];
  const float* Ws1  = (const float*)d_in[5];
  const float* bs1  = (const float*)d_in[6];
  const float* h01  = (const float*)d_in[7];
  const float* Wh_1 = (const float*)d_in[8];
  const float* bh_1 = (const float*)d_in[9];
  const float* Wz_1 = (const float*)d_in[10];
  const float* bz_1 = (const float*)d_in[11];
  const float* Ws_1 = (const float*)d_in[12];
  const float* bs_1 = (const float*)d_in[13];
  const float* h0_1 = (const float*)d_in[14];
  float* out = (float*)d_out;

  char* ws = (char*)d_ws;
  u16* WcatT = (u16*)ws;   ws += (size_t)NDIM * KDIM * 2;   // 0.75 MB
  float* bcat = (float*)ws; ws += (size_t)NDIM * 4;         // 6 KB
  u16* Abf = (u16*)ws;     ws += (size_t)MTOT * KDIM * 2;   // 32 MB
  u16* G = (u16*)ws;       ws += (size_t)MTOT * NDIM * 2;   // 192 MB
  // Summary arrays alias Abf (dead after gemm). 12 MB <= 32 MB.
  float* Acc  = (float*)Abf;
  float* Bcc  = Acc + (size_t)2 * BDIM * NCH * DDIM;
  float* Pref = Bcc + (size_t)2 * BDIM * NCH * DDIM;
  if ((size_t)(ws - (char*)d_ws) > ws_size) return;

  prep_weights<<<dim3(NDIM), dim3(KDIM), 0, stream>>>(
      Wh1, Wz1, Ws1, Wh_1, Wz_1, Ws_1, bh1, bz1, bs1, bh_1, bz_1, bs_1, WcatT, bcat);
  convert_xs<<<dim3(MTOT * KDIM / (256 * 8)), dim3(256), 0, stream>>>(xs, Abf);
  gemm_kernel<<<dim3(6144), dim3(256), 0, stream>>>(Abf, WcatT, bcat, G);
  scan_phaseA<<<dim3(2048), dim3(256), 0, stream>>>(G, Acc, Bcc);
  scan_phaseB<<<dim3(BDIM, 2), dim3(DDIM), 0, stream>>>(Acc, Bcc, h01, h0_1, Pref);
  scan_phaseC<<<dim3(2048), dim3(512), 0, stream>>>(G, Pref, out);
}